// Round 1
// baseline (1024.598 us; speedup 1.0000x reference)
//
#include <hip/hip_runtime.h>
#include <math.h>

#define BATCH 8
#define LSEQ 2048
#define DM 128
#define NH 4
#define DK 32

constexpr float SCALE = 0.17677669529663687f;   // 1/sqrt(32)
constexpr float LOG2E = 1.4426950408889634f;

// ---------- kernel 0: per-batch exclusive scan of unmasked keys ----------
// cpos[b][l] = compacted slot for key l (valid when mask==0); cnt[b] = #unmasked
__global__ __launch_bounds__(256) void scan_kernel(const float* __restrict__ mask,
                                                   int* __restrict__ cpos,
                                                   int* __restrict__ cnt)
{
    const int b = blockIdx.x;
    const int tid = threadIdx.x;
    __shared__ int ps[256];
    const float* mb = mask + (size_t)b * LSEQ;
    const int base = tid * 8;
    int loc[8];
    int sum = 0;
    #pragma unroll
    for (int i = 0; i < 8; ++i) {
        int u = (mb[base + i] == 0.0f) ? 1 : 0;
        loc[i] = sum;
        sum += u;
    }
    ps[tid] = sum;
    __syncthreads();
    for (int off = 1; off < 256; off <<= 1) {
        int v = (tid >= off) ? ps[tid - off] : 0;
        __syncthreads();
        ps[tid] += v;
        __syncthreads();
    }
    const int prev = (tid > 0) ? ps[tid - 1] : 0;
    #pragma unroll
    for (int i = 0; i < 8; ++i)
        cpos[(size_t)b * LSEQ + base + i] = prev + loc[i];
    if (tid == 255) cnt[b] = ps[255];
}

// ---------- kernel 1: QKV projection ----------
// Q stored for all l (B,H,L,32); K,V stored COMPACTED to unmasked slots.
__global__ __launch_bounds__(128) void qkv_kernel(const float* __restrict__ x,
    const float* __restrict__ Wq, const float* __restrict__ Wk, const float* __restrict__ Wv,
    const float* __restrict__ mask, const int* __restrict__ cpos,
    float* __restrict__ Q, float* __restrict__ Kc, float* __restrict__ Vc)
{
    const int b = blockIdx.x;
    const int h = blockIdx.y;
    const int l = blockIdx.z * 128 + threadIdx.x;
    const float* xb = x + (size_t)b * DM * LSEQ + l;
    const float* wq = Wq + (size_t)h * DM * DK;
    const float* wk = Wk + (size_t)h * DM * DK;
    const float* wv = Wv + (size_t)h * DM * DK;

    float qa[DK], ka[DK], va[DK];
    #pragma unroll
    for (int i = 0; i < DK; ++i) { qa[i] = 0.f; ka[i] = 0.f; va[i] = 0.f; }

    for (int d = 0; d < DM; ++d) {
        const float xv = xb[(size_t)d * LSEQ];            // coalesced across lanes
        const float4* wq4 = reinterpret_cast<const float4*>(wq + d * DK); // uniform -> s_load
        #pragma unroll
        for (int i = 0; i < 8; ++i) {
            float4 w = wq4[i];
            qa[4*i+0] = fmaf(xv, w.x, qa[4*i+0]);
            qa[4*i+1] = fmaf(xv, w.y, qa[4*i+1]);
            qa[4*i+2] = fmaf(xv, w.z, qa[4*i+2]);
            qa[4*i+3] = fmaf(xv, w.w, qa[4*i+3]);
        }
        const float4* wk4 = reinterpret_cast<const float4*>(wk + d * DK);
        #pragma unroll
        for (int i = 0; i < 8; ++i) {
            float4 w = wk4[i];
            ka[4*i+0] = fmaf(xv, w.x, ka[4*i+0]);
            ka[4*i+1] = fmaf(xv, w.y, ka[4*i+1]);
            ka[4*i+2] = fmaf(xv, w.z, ka[4*i+2]);
            ka[4*i+3] = fmaf(xv, w.w, ka[4*i+3]);
        }
        const float4* wv4 = reinterpret_cast<const float4*>(wv + d * DK);
        #pragma unroll
        for (int i = 0; i < 8; ++i) {
            float4 w = wv4[i];
            va[4*i+0] = fmaf(xv, w.x, va[4*i+0]);
            va[4*i+1] = fmaf(xv, w.y, va[4*i+1]);
            va[4*i+2] = fmaf(xv, w.z, va[4*i+2]);
            va[4*i+3] = fmaf(xv, w.w, va[4*i+3]);
        }
    }

    const int bh = b * NH + h;
    float4* qout = reinterpret_cast<float4*>(Q + ((size_t)bh * LSEQ + l) * DK);
    #pragma unroll
    for (int i = 0; i < 8; ++i)
        qout[i] = make_float4(qa[4*i], qa[4*i+1], qa[4*i+2], qa[4*i+3]);

    if (mask[(size_t)b * LSEQ + l] == 0.0f) {
        const int slot = cpos[(size_t)b * LSEQ + l];
        float4* kout = reinterpret_cast<float4*>(Kc + ((size_t)bh * LSEQ + slot) * DK);
        float4* vout = reinterpret_cast<float4*>(Vc + ((size_t)bh * LSEQ + slot) * DK);
        #pragma unroll
        for (int i = 0; i < 8; ++i) {
            kout[i] = make_float4(ka[4*i], ka[4*i+1], ka[4*i+2], ka[4*i+3]);
            vout[i] = make_float4(va[4*i], va[4*i+1], va[4*i+2], va[4*i+3]);
        }
    }
}

// ---------- kernel 2: flash attention over compacted keys ----------
// 1 query per thread; online softmax; K/V rows are wave-uniform reads.
__global__ __launch_bounds__(256) void attn_kernel(
    const float* __restrict__ Q, const float* __restrict__ Kc, const float* __restrict__ Vc,
    const float* __restrict__ mask, const int* __restrict__ cnt,
    float* __restrict__ Hd)
{
    const int bh = blockIdx.y;
    const int b = bh >> 2;
    const int h = bh & 3;
    const int q = blockIdx.x * 256 + threadIdx.x;

    const float4* q4 = reinterpret_cast<const float4*>(Q + ((size_t)bh * LSEQ + q) * DK);
    float qr[DK];
    #pragma unroll
    for (int i = 0; i < 8; ++i) {
        float4 t = q4[i];
        qr[4*i+0] = t.x; qr[4*i+1] = t.y; qr[4*i+2] = t.z; qr[4*i+3] = t.w;
    }
    float acc[DK];
    #pragma unroll
    for (int i = 0; i < DK; ++i) acc[i] = 0.f;
    float m = -INFINITY, l = 0.f;

    const int n = cnt[b];                       // uniform
    const float* Kb = Kc + (size_t)bh * LSEQ * DK;
    const float* Vb = Vc + (size_t)bh * LSEQ * DK;

    for (int j = 0; j < n; ++j) {
        const float4* k4 = reinterpret_cast<const float4*>(Kb + (size_t)j * DK);
        float s0 = 0.f, s1 = 0.f, s2 = 0.f, s3 = 0.f;
        #pragma unroll
        for (int i = 0; i < 8; ++i) {
            float4 kv = k4[i];                  // uniform address -> scalar load
            s0 = fmaf(qr[4*i+0], kv.x, s0);
            s1 = fmaf(qr[4*i+1], kv.y, s1);
            s2 = fmaf(qr[4*i+2], kv.z, s2);
            s3 = fmaf(qr[4*i+3], kv.w, s3);
        }
        const float s = ((s0 + s1) + (s2 + s3)) * SCALE;
        const float nm = fmaxf(m, s);
        const float p = exp2f((s - nm) * LOG2E);
        if (nm > m) {                            // rare after warmup (~ln n triggers)
            const float c = exp2f((m - nm) * LOG2E);
            l *= c;
            #pragma unroll
            for (int i = 0; i < DK; ++i) acc[i] *= c;
        }
        m = nm;
        l += p;
        const float4* v4 = reinterpret_cast<const float4*>(Vb + (size_t)j * DK);
        #pragma unroll
        for (int i = 0; i < 8; ++i) {
            float4 vv = v4[i];
            acc[4*i+0] = fmaf(p, vv.x, acc[4*i+0]);
            acc[4*i+1] = fmaf(p, vv.y, acc[4*i+1]);
            acc[4*i+2] = fmaf(p, vv.z, acc[4*i+2]);
            acc[4*i+3] = fmaf(p, vv.w, acc[4*i+3]);
        }
    }

    const float mq = mask[(size_t)b * LSEQ + q];    // query mask multiplies attn
    const float w = (n > 0) ? (mq / l) : 0.f;
    float4* o4 = reinterpret_cast<float4*>(Hd + ((size_t)b * LSEQ + q) * DM + h * DK);
    #pragma unroll
    for (int i = 0; i < 8; ++i)
        o4[i] = make_float4(acc[4*i+0]*w, acc[4*i+1]*w, acc[4*i+2]*w, acc[4*i+3]*w);
}

// ---------- kernel 3: output projection + transpose ----------
__global__ __launch_bounds__(256) void proj_kernel(const float* __restrict__ Hd,
    const float* __restrict__ Wo, float* __restrict__ out)
{
    const int b = blockIdx.x;
    const int l0 = blockIdx.y * 64;
    __shared__ float ht[64 * 129];                 // pad 129 -> 2-way (free) on reads
    const int tid = threadIdx.x;
    const float4* src = reinterpret_cast<const float4*>(Hd + ((size_t)b * LSEQ + l0) * DM);
    #pragma unroll
    for (int i = 0; i < 8; ++i) {
        int idx = tid + 256 * i;                   // 2048 float4s = 64x128 tile
        int r = idx >> 5;
        int c = (idx & 31) * 4;
        float4 v = src[idx];
        ht[r * 129 + c + 0] = v.x;
        ht[r * 129 + c + 1] = v.y;
        ht[r * 129 + c + 2] = v.z;
        ht[r * 129 + c + 3] = v.w;
    }
    __syncthreads();
    const int lt = tid & 63;
    const int jq = tid >> 6;                       // wave id -> j-quarter (uniform per wave)
    float acc[32];
    #pragma unroll
    for (int i = 0; i < 32; ++i) acc[i] = 0.f;
    for (int i = 0; i < DM; ++i) {
        const float hv = ht[lt * 129 + i];
        const float4* w4 = reinterpret_cast<const float4*>(Wo + (size_t)i * DM + jq * 32); // uniform
        #pragma unroll
        for (int u = 0; u < 8; ++u) {
            float4 w = w4[u];
            acc[4*u+0] = fmaf(hv, w.x, acc[4*u+0]);
            acc[4*u+1] = fmaf(hv, w.y, acc[4*u+1]);
            acc[4*u+2] = fmaf(hv, w.z, acc[4*u+2]);
            acc[4*u+3] = fmaf(hv, w.w, acc[4*u+3]);
        }
    }
    float* ob = out + (size_t)b * DM * LSEQ + (size_t)(jq * 32) * LSEQ + l0 + lt;
    #pragma unroll
    for (int j = 0; j < 32; ++j)
        ob[(size_t)j * LSEQ] = acc[j];             // coalesced across lt
}

extern "C" void kernel_launch(void* const* d_in, const int* in_sizes, int n_in,
                              void* d_out, int out_size, void* d_ws, size_t ws_size,
                              hipStream_t stream)
{
    const float* x    = (const float*)d_in[0];
    const float* mask = (const float*)d_in[1];
    const float* Wq   = (const float*)d_in[2];
    const float* Wk   = (const float*)d_in[3];
    const float* Wv   = (const float*)d_in[4];
    const float* Wo   = (const float*)d_in[5];
    float* out = (float*)d_out;

    float* ws = (float*)d_ws;
    const size_t NQKV = (size_t)BATCH * NH * LSEQ * DK;   // 2,097,152 floats
    float* Q  = ws;
    float* Kc = ws + NQKV;
    float* Vc = ws + 2 * NQKV;
    float* Hd = ws + 3 * NQKV;                            // (B, L, 128)
    int* cpos = (int*)(ws + 4 * NQKV);
    int* cnt  = cpos + (size_t)BATCH * LSEQ;

    scan_kernel<<<dim3(BATCH), dim3(256), 0, stream>>>(mask, cpos, cnt);
    qkv_kernel<<<dim3(BATCH, NH, LSEQ / 128), dim3(128), 0, stream>>>(
        x, Wq, Wk, Wv, mask, cpos, Q, Kc, Vc);
    attn_kernel<<<dim3(LSEQ / 256, BATCH * NH), dim3(256), 0, stream>>>(
        Q, Kc, Vc, mask, cnt, Hd);
    proj_kernel<<<dim3(BATCH, LSEQ / 64), dim3(256), 0, stream>>>(Hd, Wo, out);
}

// Round 2
// 544.874 us; speedup vs baseline: 1.8804x; 1.8804x over previous
//
#include <hip/hip_runtime.h>
#include <math.h>

#define BATCH 8
#define LSEQ 2048
#define DM 128
#define NH 4
#define DK 32

constexpr float SCALE = 0.17677669529663687f;   // 1/sqrt(32)
constexpr float LOG2E = 1.4426950408889634f;
constexpr float SL = SCALE * LOG2E;             // folded into exp2

// ---------- kernel 0: per-batch exclusive scan of unmasked keys ----------
__global__ __launch_bounds__(256) void scan_kernel(const float* __restrict__ mask,
                                                   int* __restrict__ cpos,
                                                   int* __restrict__ cnt)
{
    const int b = blockIdx.x;
    const int tid = threadIdx.x;
    __shared__ int ps[256];
    const float* mb = mask + (size_t)b * LSEQ;
    const int base = tid * 8;
    int loc[8];
    int sum = 0;
    #pragma unroll
    for (int i = 0; i < 8; ++i) {
        int u = (mb[base + i] == 0.0f) ? 1 : 0;
        loc[i] = sum;
        sum += u;
    }
    ps[tid] = sum;
    __syncthreads();
    for (int off = 1; off < 256; off <<= 1) {
        int v = (tid >= off) ? ps[tid - off] : 0;
        __syncthreads();
        ps[tid] += v;
        __syncthreads();
    }
    const int prev = (tid > 0) ? ps[tid - 1] : 0;
    #pragma unroll
    for (int i = 0; i < 8; ++i)
        cpos[(size_t)b * LSEQ + base + i] = prev + loc[i];
    if (tid == 255) cnt[b] = ps[255];
}

// ---------- kernel 1: QKV projection, one of {Q,K,V} per block ----------
__global__ __launch_bounds__(128) void qkv_kernel(const float* __restrict__ x,
    const float* __restrict__ Wq, const float* __restrict__ Wk, const float* __restrict__ Wv,
    const float* __restrict__ mask, const int* __restrict__ cpos,
    float* __restrict__ Q, float* __restrict__ Kc, float* __restrict__ Vc)
{
    const int b = blockIdx.x & 7;
    const int which = blockIdx.x >> 3;            // 0=Q 1=K 2=V
    const int h = blockIdx.y;
    const int l = blockIdx.z * 128 + threadIdx.x;
    const float* xb = x + (size_t)b * DM * LSEQ + l;
    const float* W = (which == 0 ? Wq : (which == 1 ? Wk : Wv)) + (size_t)h * DM * DK;

    float a[DK];
    #pragma unroll
    for (int i = 0; i < DK; ++i) a[i] = 0.f;

    for (int d = 0; d < DM; ++d) {
        const float xv = xb[(size_t)d * LSEQ];                         // coalesced
        const float4* w4 = reinterpret_cast<const float4*>(W + d * DK); // uniform -> scalar
        #pragma unroll
        for (int i = 0; i < 8; ++i) {
            float4 w = w4[i];
            a[4*i+0] = fmaf(xv, w.x, a[4*i+0]);
            a[4*i+1] = fmaf(xv, w.y, a[4*i+1]);
            a[4*i+2] = fmaf(xv, w.z, a[4*i+2]);
            a[4*i+3] = fmaf(xv, w.w, a[4*i+3]);
        }
    }

    const int bh = b * NH + h;
    if (which == 0) {
        float4* o = reinterpret_cast<float4*>(Q + ((size_t)bh * LSEQ + l) * DK);
        #pragma unroll
        for (int i = 0; i < 8; ++i)
            o[i] = make_float4(a[4*i], a[4*i+1], a[4*i+2], a[4*i+3]);
    } else if (mask[(size_t)b * LSEQ + l] == 0.0f) {
        const int slot = cpos[(size_t)b * LSEQ + l];
        float* dst = (which == 1 ? Kc : Vc) + ((size_t)bh * LSEQ + slot) * DK;
        float4* o = reinterpret_cast<float4*>(dst);
        #pragma unroll
        for (int i = 0; i < 8; ++i)
            o[i] = make_float4(a[4*i], a[4*i+1], a[4*i+2], a[4*i+3]);
    }
}

// ---------- kernel 2: flash attention, 64 queries/block, 4 key-chunk waves ----------
__global__ __launch_bounds__(256, 4) void attn_kernel(
    const float* __restrict__ Q, const float* __restrict__ Kc, const float* __restrict__ Vc,
    const float* __restrict__ mask, const int* __restrict__ cnt,
    float* __restrict__ Hd)
{
    const int bh = blockIdx.y;
    const int b = bh >> 2;
    const int h = bh & 3;
    const int lane = threadIdx.x & 63;            // = query within tile
    const int wv = threadIdx.x >> 6;              // wave id = key chunk
    const int q = blockIdx.x * 64 + lane;

    float qr[DK];
    const float4* q4 = reinterpret_cast<const float4*>(Q + ((size_t)bh * LSEQ + q) * DK);
    #pragma unroll
    for (int i = 0; i < 8; ++i) {
        float4 t = q4[i];
        qr[4*i+0] = t.x; qr[4*i+1] = t.y; qr[4*i+2] = t.z; qr[4*i+3] = t.w;
    }

    float acc[DK];
    #pragma unroll
    for (int i = 0; i < DK; ++i) acc[i] = 0.f;
    float l = 0.f;

    const int n = cnt[b];                         // uniform
    const int c0 = (n * wv) >> 2;
    const int c1 = (n * (wv + 1)) >> 2;
    const float* Kb = Kc + (size_t)bh * LSEQ * DK;
    const float* Vb = Vc + (size_t)bh * LSEQ * DK;

    for (int j = c0; j < c1; ++j) {
        const float4* k4 = reinterpret_cast<const float4*>(Kb + (size_t)j * DK);
        float s0 = 0.f, s1 = 0.f, s2 = 0.f, s3 = 0.f;
        #pragma unroll
        for (int i = 0; i < 8; ++i) {
            float4 kv = k4[i];                    // wave-uniform -> broadcast
            s0 = fmaf(qr[4*i+0], kv.x, s0);
            s1 = fmaf(qr[4*i+1], kv.y, s1);
            s2 = fmaf(qr[4*i+2], kv.z, s2);
            s3 = fmaf(qr[4*i+3], kv.w, s3);
        }
        const float p = exp2f(((s0 + s1) + (s2 + s3)) * SL);   // fixed-max softmax
        l += p;
        const float4* v4 = reinterpret_cast<const float4*>(Vb + (size_t)j * DK);
        #pragma unroll
        for (int i = 0; i < 8; ++i) {
            float4 vv = v4[i];
            acc[4*i+0] = fmaf(p, vv.x, acc[4*i+0]);
            acc[4*i+1] = fmaf(p, vv.y, acc[4*i+1]);
            acc[4*i+2] = fmaf(p, vv.z, acc[4*i+2]);
            acc[4*i+3] = fmaf(p, vv.w, acc[4*i+3]);
        }
    }

    // merge the 4 wave-partials (pure sums) via LDS
    __shared__ float red[3][DK + 1][64];
    if (wv > 0) {
        #pragma unroll
        for (int i = 0; i < DK; ++i) red[wv - 1][i][lane] = acc[i];
        red[wv - 1][DK][lane] = l;
    }
    __syncthreads();
    if (wv == 0) {
        #pragma unroll
        for (int c = 0; c < 3; ++c) {
            #pragma unroll
            for (int i = 0; i < DK; ++i) acc[i] += red[c][i][lane];
            l += red[c][DK][lane];
        }
        const float mq = mask[(size_t)b * LSEQ + q];
        const float wgt = (l > 0.f) ? (mq / l) : 0.f;
        float4* o4 = reinterpret_cast<float4*>(Hd + ((size_t)b * LSEQ + q) * DM + h * DK);
        #pragma unroll
        for (int i = 0; i < 8; ++i)
            o4[i] = make_float4(acc[4*i+0]*wgt, acc[4*i+1]*wgt, acc[4*i+2]*wgt, acc[4*i+3]*wgt);
    }
}

// ---------- kernel 3: output projection + transpose, 16-row tiles ----------
__global__ __launch_bounds__(256) void proj_kernel(const float* __restrict__ Hd,
    const float* __restrict__ Wo, float* __restrict__ out)
{
    const int b = blockIdx.x;
    const int l0 = blockIdx.y * 16;
    __shared__ float ht[16 * 129];                // stride 129 -> conflict-free reads
    const int tid = threadIdx.x;
    const float4* src = reinterpret_cast<const float4*>(Hd + ((size_t)b * LSEQ + l0) * DM);
    #pragma unroll
    for (int i = 0; i < 2; ++i) {
        int idx = tid + 256 * i;                  // 512 float4 = 16x128 tile
        int r = idx >> 5;
        int c = (idx & 31) * 4;
        float4 v = src[idx];
        ht[r * 129 + c + 0] = v.x;
        ht[r * 129 + c + 1] = v.y;
        ht[r * 129 + c + 2] = v.z;
        ht[r * 129 + c + 3] = v.w;
    }
    __syncthreads();
    const int lt = tid & 15;                      // query row
    const int jg = tid >> 4;                      // 16 groups x 8 outputs
    float acc[8];
    #pragma unroll
    for (int i = 0; i < 8; ++i) acc[i] = 0.f;
    for (int i = 0; i < DM; ++i) {
        const float hv = ht[lt * 129 + i];
        const float4* w4 = reinterpret_cast<const float4*>(Wo + (size_t)i * DM + jg * 8);
        float4 w0 = w4[0], w1 = w4[1];
        acc[0] = fmaf(hv, w0.x, acc[0]);
        acc[1] = fmaf(hv, w0.y, acc[1]);
        acc[2] = fmaf(hv, w0.z, acc[2]);
        acc[3] = fmaf(hv, w0.w, acc[3]);
        acc[4] = fmaf(hv, w1.x, acc[4]);
        acc[5] = fmaf(hv, w1.y, acc[5]);
        acc[6] = fmaf(hv, w1.z, acc[6]);
        acc[7] = fmaf(hv, w1.w, acc[7]);
    }
    float* ob = out + (size_t)b * DM * LSEQ + (size_t)(jg * 8) * LSEQ + l0 + lt;
    #pragma unroll
    for (int j = 0; j < 8; ++j)
        ob[(size_t)j * LSEQ] = acc[j];            // coalesced across lt
}

extern "C" void kernel_launch(void* const* d_in, const int* in_sizes, int n_in,
                              void* d_out, int out_size, void* d_ws, size_t ws_size,
                              hipStream_t stream)
{
    const float* x    = (const float*)d_in[0];
    const float* mask = (const float*)d_in[1];
    const float* Wq   = (const float*)d_in[2];
    const float* Wk   = (const float*)d_in[3];
    const float* Wv   = (const float*)d_in[4];
    const float* Wo   = (const float*)d_in[5];
    float* out = (float*)d_out;

    float* ws = (float*)d_ws;
    const size_t NQKV = (size_t)BATCH * NH * LSEQ * DK;   // 2,097,152 floats
    float* Q  = ws;
    float* Kc = ws + NQKV;
    float* Vc = ws + 2 * NQKV;
    float* Hd = ws + 3 * NQKV;                            // (B, L, 128)
    int* cpos = (int*)(ws + 4 * NQKV);
    int* cnt  = cpos + (size_t)BATCH * LSEQ;

    scan_kernel<<<dim3(BATCH), dim3(256), 0, stream>>>(mask, cpos, cnt);
    qkv_kernel<<<dim3(BATCH * 3, NH, LSEQ / 128), dim3(128), 0, stream>>>(
        x, Wq, Wk, Wv, mask, cpos, Q, Kc, Vc);
    attn_kernel<<<dim3(LSEQ / 64, BATCH * NH), dim3(256), 0, stream>>>(
        Q, Kc, Vc, mask, cnt, Hd);
    proj_kernel<<<dim3(BATCH, LSEQ / 16), dim3(256), 0, stream>>>(Hd, Wo, out);
}

// Round 3
// 113.371 us; speedup vs baseline: 9.0375x; 4.8061x over previous
//
#include <hip/hip_runtime.h>
#include <hip/hip_bf16.h>
#include <math.h>

#define BATCH 8
#define LSEQ 2048
#define DM 128
#define NH 4
#define DK 32

constexpr float SCALE = 0.17677669529663687f;   // 1/sqrt(32)
constexpr float LOG2E = 1.4426950408889634f;
constexpr float SL = SCALE * LOG2E;

typedef __attribute__((ext_vector_type(8))) __bf16 bf16x8;
typedef __attribute__((ext_vector_type(16))) float f32x16;

__device__ __forceinline__ bf16x8 as_bf16x8(uint4 u) {
    union { uint4 a; bf16x8 b; } c; c.a = u; return c.b;
}
__device__ __forceinline__ unsigned pack_bf2(float lo, float hi) {
    __hip_bfloat162 h = __float22bfloat162_rn(make_float2(lo, hi));
    union { __hip_bfloat162 a; unsigned b; } c; c.a = h; return c.b;
}

// ---------- kernel 0: per-batch exclusive scan of unmasked keys ----------
__global__ __launch_bounds__(256) void scan_kernel(const float* __restrict__ mask,
                                                   int* __restrict__ cpos,
                                                   int* __restrict__ cnt)
{
    const int b = blockIdx.x;
    const int tid = threadIdx.x;
    __shared__ int ps[256];
    const float* mb = mask + (size_t)b * LSEQ;
    const int base = tid * 8;
    int loc[8];
    int sum = 0;
    #pragma unroll
    for (int i = 0; i < 8; ++i) {
        int u = (mb[base + i] == 0.0f) ? 1 : 0;
        loc[i] = sum;
        sum += u;
    }
    ps[tid] = sum;
    __syncthreads();
    for (int off = 1; off < 256; off <<= 1) {
        int v = (tid >= off) ? ps[tid - off] : 0;
        __syncthreads();
        ps[tid] += v;
        __syncthreads();
    }
    const int prev = (tid > 0) ? ps[tid - 1] : 0;
    #pragma unroll
    for (int i = 0; i < 8; ++i)
        cpos[(size_t)b * LSEQ + base + i] = prev + loc[i];
    if (tid == 255) cnt[b] = ps[255];
}

// ---------- kernel 1: QKV projection -> bf16 outputs ----------
__global__ __launch_bounds__(128) void qkv_kernel(const float* __restrict__ x,
    const float* __restrict__ Wq, const float* __restrict__ Wk, const float* __restrict__ Wv,
    const float* __restrict__ mask, const int* __restrict__ cpos,
    unsigned short* __restrict__ Qb, unsigned short* __restrict__ Kb,
    unsigned short* __restrict__ Vcb)
{
    const int b = blockIdx.x & 7;
    const int which = blockIdx.x >> 3;            // 0=Q 1=K 2=V
    const int h = blockIdx.y;
    const int l = blockIdx.z * 128 + threadIdx.x;
    const float* xb = x + (size_t)b * DM * LSEQ + l;
    const float* W = (which == 0 ? Wq : (which == 1 ? Wk : Wv)) + (size_t)h * DM * DK;

    float a[DK];
    #pragma unroll
    for (int i = 0; i < DK; ++i) a[i] = 0.f;

    for (int d = 0; d < DM; ++d) {
        const float xv = xb[(size_t)d * LSEQ];                          // coalesced
        const float4* w4 = reinterpret_cast<const float4*>(W + d * DK); // uniform
        #pragma unroll
        for (int i = 0; i < 8; ++i) {
            float4 w = w4[i];
            a[4*i+0] = fmaf(xv, w.x, a[4*i+0]);
            a[4*i+1] = fmaf(xv, w.y, a[4*i+1]);
            a[4*i+2] = fmaf(xv, w.z, a[4*i+2]);
            a[4*i+3] = fmaf(xv, w.w, a[4*i+3]);
        }
    }

    unsigned pw[16];
    #pragma unroll
    for (int i = 0; i < 16; ++i) pw[i] = pack_bf2(a[2*i], a[2*i+1]);

    const int bh = b * NH + h;
    unsigned short* dst = nullptr;
    size_t row = 0;
    if (which == 0) {
        dst = Qb; row = (size_t)bh * LSEQ + l;
    } else if (mask[(size_t)b * LSEQ + l] == 0.0f) {
        dst = (which == 1 ? Kb : Vcb);
        row = (size_t)bh * LSEQ + cpos[(size_t)b * LSEQ + l];
    }
    if (dst) {
        uint4* o = reinterpret_cast<uint4*>(dst + row * DK);
        o[0] = make_uint4(pw[0],  pw[1],  pw[2],  pw[3]);
        o[1] = make_uint4(pw[4],  pw[5],  pw[6],  pw[7]);
        o[2] = make_uint4(pw[8],  pw[9],  pw[10], pw[11]);
        o[3] = make_uint4(pw[12], pw[13], pw[14], pw[15]);
    }
}

// ---------- kernel 1b: transpose Vcb[slot][32] -> Vt[d][slot] (bf16) ----------
__global__ __launch_bounds__(256) void vtrans_kernel(const unsigned short* __restrict__ Vcb,
                                                     unsigned short* __restrict__ Vt)
{
    const int bh = blockIdx.y;
    const int s0 = blockIdx.x * 256;
    __shared__ unsigned lds[256][17];
    const int t = threadIdx.x;
    const uint4* src = reinterpret_cast<const uint4*>(Vcb + ((size_t)bh * LSEQ + s0 + t) * DK);
    uint4 r0 = src[0], r1 = src[1], r2 = src[2], r3 = src[3];
    unsigned* lr = lds[t];
    lr[0]=r0.x;  lr[1]=r0.y;  lr[2]=r0.z;  lr[3]=r0.w;
    lr[4]=r1.x;  lr[5]=r1.y;  lr[6]=r1.z;  lr[7]=r1.w;
    lr[8]=r2.x;  lr[9]=r2.y;  lr[10]=r2.z; lr[11]=r2.w;
    lr[12]=r3.x; lr[13]=r3.y; lr[14]=r3.z; lr[15]=r3.w;
    __syncthreads();
    const int d = t & 31;
    const int c = (t >> 5) * 32;
    const int dw = d >> 1;
    const int dh = (d & 1) * 16;
    unsigned ow[16];
    #pragma unroll
    for (int i = 0; i < 16; ++i) {
        unsigned lo = (lds[c + 2*i][dw] >> dh) & 0xffffu;
        unsigned hv = (lds[c + 2*i + 1][dw] >> dh) & 0xffffu;
        ow[i] = lo | (hv << 16);
    }
    uint4* dstp = reinterpret_cast<uint4*>(Vt + ((size_t)bh * DK + d) * LSEQ + s0 + c);
    dstp[0] = make_uint4(ow[0],  ow[1],  ow[2],  ow[3]);
    dstp[1] = make_uint4(ow[4],  ow[5],  ow[6],  ow[7]);
    dstp[2] = make_uint4(ow[8],  ow[9],  ow[10], ow[11]);
    dstp[3] = make_uint4(ow[12], ow[13], ow[14], ow[15]);
}

// ---------- kernel 2: MFMA flash attention ----------
__global__ __launch_bounds__(128, 4) void attn_kernel(
    const unsigned short* __restrict__ Qb, const unsigned short* __restrict__ Kb,
    const unsigned short* __restrict__ Vt, const float* __restrict__ mask,
    const int* __restrict__ cnt, float* __restrict__ Hd)
{
    const int bh = blockIdx.y;
    const int b = bh >> 2;
    const int h = bh & 3;
    const int lane = threadIdx.x & 63;
    const int kw = threadIdx.x >> 6;              // key-half owner
    const int ql = lane & 31;
    const int hi = lane >> 5;
    const int q0 = blockIdx.x * 32;
    const int n = cnt[b];

    const uint4* Qp = reinterpret_cast<const uint4*>(Qb + ((size_t)bh * LSEQ + q0 + ql) * DK);
    const bf16x8 qf0 = as_bf16x8(Qp[hi]);         // Q[q=ql][d=8*hi+i]
    const bf16x8 qf1 = as_bf16x8(Qp[2 + hi]);     // d = 16+8*hi+i

    const unsigned short* Kbase = Kb + (size_t)bh * LSEQ * DK;
    const unsigned short* Vbase = Vt + ((size_t)bh * DK + ql) * LSEQ;

    f32x16 acc;
    #pragma unroll
    for (int r = 0; r < 16; ++r) acc[r] = 0.f;
    f32x16 zero;
    #pragma unroll
    for (int r = 0; r < 16; ++r) zero[r] = 0.f;
    float lacc = 0.f;

    auto tile = [&](int k0, bool pred) {
        const uint4* Kp = reinterpret_cast<const uint4*>(Kbase + (size_t)(k0 + ql) * DK);
        bf16x8 kf0 = as_bf16x8(Kp[hi]);           // K[key=ql][d=8*hi+i]
        bf16x8 kf1 = as_bf16x8(Kp[2 + hi]);
        f32x16 s = __builtin_amdgcn_mfma_f32_32x32x16_bf16(kf0, qf0, zero, 0, 0, 0);
        s = __builtin_amdgcn_mfma_f32_32x32x16_bf16(kf1, qf1, s, 0, 0, 0);
        const uint4* Vp = reinterpret_cast<const uint4*>(Vbase + k0);
        bf16x8 vf0 = as_bf16x8(Vp[hi]);           // Vt[d=ql][k0+8*hi+i]
        bf16x8 vf1 = as_bf16x8(Vp[2 + hi]);       // keys k0+16..k0+31
        unsigned w[8], sw[8];
        #pragma unroll
        for (int j = 0; j < 8; ++j) {
            float e0 = exp2f(s[2*j]   * SL);      // key = k0+(r&3)+8*(r>>2)+4*hi
            float e1 = exp2f(s[2*j+1] * SL);
            if (pred) {
                const int r0 = 2*j, r1 = 2*j + 1;
                if (k0 + (r0 & 3) + 8*(r0 >> 2) + 4*hi >= n) e0 = 0.f;
                if (k0 + (r1 & 3) + 8*(r1 >> 2) + 4*hi >= n) e1 = 0.f;
            }
            lacc += e0 + e1;
            w[j] = pack_bf2(e0, e1);
        }
        #pragma unroll
        for (int j = 0; j < 8; ++j) sw[j] = __shfl_xor(w[j], 32);
        uint4 b0 = hi ? make_uint4(sw[2], sw[3], w[2], w[3])
                      : make_uint4(w[0], w[1], sw[0], sw[1]);
        uint4 b1 = hi ? make_uint4(sw[6], sw[7], w[6], w[7])
                      : make_uint4(w[4], w[5], sw[4], sw[5]);
        acc = __builtin_amdgcn_mfma_f32_32x32x16_bf16(vf0, as_bf16x8(b0), acc, 0, 0, 0);
        acc = __builtin_amdgcn_mfma_f32_32x32x16_bf16(vf1, as_bf16x8(b1), acc, 0, 0, 0);
    };

    const int nfull = n & ~31;
    for (int k0 = kw * 32; k0 < nfull; k0 += 64) tile(k0, false);
    if (n & 31) {
        if (((nfull >> 5) & 1) == kw) tile(nfull, true);
    }

    __shared__ float red[64][18];
    if (kw == 1) {
        #pragma unroll
        for (int r = 0; r < 16; ++r) red[lane][r] = acc[r];
        red[lane][16] = lacc;
    }
    __syncthreads();
    if (kw == 0) {
        #pragma unroll
        for (int r = 0; r < 16; ++r) acc[r] += red[lane][r];
        lacc += red[lane][16];
        const float lf = lacc + __shfl_xor(lacc, 32);
        const float mq = mask[(size_t)b * LSEQ + q0 + ql];
        const float wgt = (lf > 0.f) ? (mq / lf) : 0.f;
        float* orow = Hd + ((size_t)b * LSEQ + q0 + ql) * DM + h * DK + 4 * hi;
        #pragma unroll
        for (int g = 0; g < 4; ++g) {            // d = 8g + 4hi + (0..3)
            float4 o = make_float4(acc[4*g]*wgt, acc[4*g+1]*wgt,
                                   acc[4*g+2]*wgt, acc[4*g+3]*wgt);
            *reinterpret_cast<float4*>(orow + 8*g) = o;
        }
    }
}

// ---------- kernel 3: output projection + transpose ----------
__global__ __launch_bounds__(256) void proj_kernel(const float* __restrict__ Hd,
    const float* __restrict__ Wo, float* __restrict__ out)
{
    const int b = blockIdx.x;
    const int l0 = blockIdx.y * 16;
    __shared__ float ht[16 * 129];
    const int tid = threadIdx.x;
    const float4* src = reinterpret_cast<const float4*>(Hd + ((size_t)b * LSEQ + l0) * DM);
    #pragma unroll
    for (int i = 0; i < 2; ++i) {
        int idx = tid + 256 * i;
        int r = idx >> 5;
        int c = (idx & 31) * 4;
        float4 v = src[idx];
        ht[r * 129 + c + 0] = v.x;
        ht[r * 129 + c + 1] = v.y;
        ht[r * 129 + c + 2] = v.z;
        ht[r * 129 + c + 3] = v.w;
    }
    __syncthreads();
    const int lt = tid & 15;
    const int jg = tid >> 4;
    float acc[8];
    #pragma unroll
    for (int i = 0; i < 8; ++i) acc[i] = 0.f;
    for (int i = 0; i < DM; ++i) {
        const float hv = ht[lt * 129 + i];
        const float4* w4 = reinterpret_cast<const float4*>(Wo + (size_t)i * DM + jg * 8);
        float4 w0 = w4[0], w1 = w4[1];
        acc[0] = fmaf(hv, w0.x, acc[0]);
        acc[1] = fmaf(hv, w0.y, acc[1]);
        acc[2] = fmaf(hv, w0.z, acc[2]);
        acc[3] = fmaf(hv, w0.w, acc[3]);
        acc[4] = fmaf(hv, w1.x, acc[4]);
        acc[5] = fmaf(hv, w1.y, acc[5]);
        acc[6] = fmaf(hv, w1.z, acc[6]);
        acc[7] = fmaf(hv, w1.w, acc[7]);
    }
    float* ob = out + (size_t)b * DM * LSEQ + (size_t)(jg * 8) * LSEQ + l0 + lt;
    #pragma unroll
    for (int j = 0; j < 8; ++j)
        ob[(size_t)j * LSEQ] = acc[j];
}

extern "C" void kernel_launch(void* const* d_in, const int* in_sizes, int n_in,
                              void* d_out, int out_size, void* d_ws, size_t ws_size,
                              hipStream_t stream)
{
    const float* x    = (const float*)d_in[0];
    const float* mask = (const float*)d_in[1];
    const float* Wq   = (const float*)d_in[2];
    const float* Wk   = (const float*)d_in[3];
    const float* Wv   = (const float*)d_in[4];
    const float* Wo   = (const float*)d_in[5];
    float* out = (float*)d_out;

    char* wsb = (char*)d_ws;
    const size_t NBF = (size_t)BATCH * NH * LSEQ * DK;      // 2,097,152 elems
    unsigned short* Qb  = (unsigned short*)wsb;             // 4MB
    unsigned short* Kb  = Qb + NBF;                         // 4MB
    unsigned short* Vcb = Kb + NBF;                         // 4MB
    unsigned short* Vt  = Vcb + NBF;                        // 4MB
    float* Hd = (float*)(wsb + 16ull * 1024 * 1024);        // 8MB (B,L,128) f32
    int* cpos = (int*)(wsb + 24ull * 1024 * 1024);
    int* cnt  = cpos + (size_t)BATCH * LSEQ;

    scan_kernel<<<dim3(BATCH), dim3(256), 0, stream>>>(mask, cpos, cnt);
    qkv_kernel<<<dim3(BATCH * 3, NH, LSEQ / 128), dim3(128), 0, stream>>>(
        x, Wq, Wk, Wv, mask, cpos, Qb, Kb, Vcb);
    vtrans_kernel<<<dim3(LSEQ / 256, BATCH * NH), dim3(256), 0, stream>>>(Vcb, Vt);
    attn_kernel<<<dim3(LSEQ / 32, BATCH * NH), dim3(128), 0, stream>>>(
        Qb, Kb, Vt, mask, cnt, Hd);
    proj_kernel<<<dim3(BATCH, LSEQ / 16), dim3(256), 0, stream>>>(Hd, Wo, out);
}

// Round 4
// 85.227 us; speedup vs baseline: 12.0220x; 1.3302x over previous
//
#include <hip/hip_runtime.h>
#include <hip/hip_bf16.h>
#include <math.h>

#define BATCH 8
#define LSEQ 2048
#define DM 128
#define NH 4
#define DK 32

constexpr float SCALE = 0.17677669529663687f;   // 1/sqrt(32)
constexpr float LOG2E = 1.4426950408889634f;
constexpr float SL = SCALE * LOG2E;

typedef __attribute__((ext_vector_type(8))) __bf16 bf16x8;
typedef __attribute__((ext_vector_type(16))) float f32x16;

__device__ __forceinline__ bf16x8 as_bf16x8(uint4 u) {
    union { uint4 a; bf16x8 b; } c; c.a = u; return c.b;
}
__device__ __forceinline__ unsigned pack_bf2(float lo, float hi) {
    __hip_bfloat162 h = __float22bfloat162_rn(make_float2(lo, hi));
    union { __hip_bfloat162 a; unsigned b; } c; c.a = h; return c.b;
}

// ---------- kernel 0: per-batch exclusive scan of unmasked keys ----------
__global__ __launch_bounds__(256) void scan_kernel(const float* __restrict__ mask,
                                                   int* __restrict__ cpos,
                                                   int* __restrict__ cnt)
{
    const int b = blockIdx.x;
    const int tid = threadIdx.x;
    __shared__ int ps[256];
    const float* mb = mask + (size_t)b * LSEQ;
    const int base = tid * 8;
    int loc[8];
    int sum = 0;
    #pragma unroll
    for (int i = 0; i < 8; ++i) {
        int u = (mb[base + i] == 0.0f) ? 1 : 0;
        loc[i] = sum;
        sum += u;
    }
    ps[tid] = sum;
    __syncthreads();
    for (int off = 1; off < 256; off <<= 1) {
        int v = (tid >= off) ? ps[tid - off] : 0;
        __syncthreads();
        ps[tid] += v;
        __syncthreads();
    }
    const int prev = (tid > 0) ? ps[tid - 1] : 0;
    #pragma unroll
    for (int i = 0; i < 8; ++i)
        cpos[(size_t)b * LSEQ + base + i] = prev + loc[i];
    if (tid == 255) cnt[b] = ps[255];
}

// ---------- kernel 1: QKV projection via MFMA ----------
// One block: (b, which, 64-l tile). 4 waves: (l-sub 32) x (head pair).
// D[o][l] = sum_d W[d][o] * x[d][l]; A-frag = W (lane=o), B-frag = x (lane=l).
// Each lane owns output row l for 2 heads -> per-lane row store w/ compaction.
__global__ __launch_bounds__(256) void qkv_mfma_kernel(const float* __restrict__ x,
    const float* __restrict__ Wq, const float* __restrict__ Wk, const float* __restrict__ Wv,
    const float* __restrict__ mask, const int* __restrict__ cpos,
    unsigned short* __restrict__ Qb, unsigned short* __restrict__ Kb,
    unsigned short* __restrict__ Vcb)
{
    const int b = blockIdx.x;                 // 8
    const int which = blockIdx.y;             // 0=Q 1=K 2=V
    const int lt = blockIdx.z;                // 32 tiles of 64 l
    const int tid = threadIdx.x;
    const int wv = tid >> 6;                  // 4 waves
    const int lane = tid & 63;
    const int ql = lane & 31;
    const int hi = lane >> 5;
    const int l = lt * 64 + (wv & 1) * 32 + ql;   // this lane's output row
    const int hbase = (wv >> 1) * 2;              // head pair

    const float* W = (which == 0 ? Wq : (which == 1 ? Wk : Wv));
    const float* xcol = x + (size_t)b * DM * LSEQ + l;   // x[b][d][l]

    f32x16 acc0, acc1;
    #pragma unroll
    for (int r = 0; r < 16; ++r) { acc0[r] = 0.f; acc1[r] = 0.f; }

    #pragma unroll
    for (int d0 = 0; d0 < DM; d0 += 16) {
        const int dbase = d0 + 8 * hi;
        // x fragment: B[col=l][k=dbase+i] -- coalesced per i
        float xv[8];
        #pragma unroll
        for (int i = 0; i < 8; ++i) xv[i] = xcol[(size_t)(dbase + i) * LSEQ];
        uint4 xp = make_uint4(pack_bf2(xv[0], xv[1]), pack_bf2(xv[2], xv[3]),
                              pack_bf2(xv[4], xv[5]), pack_bf2(xv[6], xv[7]));
        const bf16x8 xf = as_bf16x8(xp);
        // W fragments for the two heads: A[row=o=ql][k=dbase+i]
        const float* wr0 = W + ((size_t)(hbase + 0) * DM + dbase) * DK + ql;
        const float* wr1 = W + ((size_t)(hbase + 1) * DM + dbase) * DK + ql;
        float w0[8], w1[8];
        #pragma unroll
        for (int i = 0; i < 8; ++i) { w0[i] = wr0[i * DK]; w1[i] = wr1[i * DK]; }
        uint4 wp0 = make_uint4(pack_bf2(w0[0], w0[1]), pack_bf2(w0[2], w0[3]),
                               pack_bf2(w0[4], w0[5]), pack_bf2(w0[6], w0[7]));
        uint4 wp1 = make_uint4(pack_bf2(w1[0], w1[1]), pack_bf2(w1[2], w1[3]),
                               pack_bf2(w1[4], w1[5]), pack_bf2(w1[6], w1[7]));
        acc0 = __builtin_amdgcn_mfma_f32_32x32x16_bf16(as_bf16x8(wp0), xf, acc0, 0, 0, 0);
        acc1 = __builtin_amdgcn_mfma_f32_32x32x16_bf16(as_bf16x8(wp1), xf, acc1, 0, 0, 0);
    }

    // store: row l (Q) or compacted slot (K/V); dk(r) = (r&3)+8*(r>>2)+4*hi
    bool store = true;
    int slot = l;
    if (which != 0) {
        if (mask[(size_t)b * LSEQ + l] == 0.0f) slot = cpos[(size_t)b * LSEQ + l];
        else store = false;
    }
    if (store) {
        unsigned short* base0 = (which == 0 ? Qb : (which == 1 ? Kb : Vcb));
        #pragma unroll
        for (int hh = 0; hh < 2; ++hh) {
            const f32x16& A = hh ? acc1 : acc0;
            const int bh = b * NH + hbase + hh;
            unsigned short* rowp = base0 + ((size_t)bh * LSEQ + slot) * DK;
            unsigned dw[8];
            #pragma unroll
            for (int j = 0; j < 8; ++j) dw[j] = pack_bf2(A[2*j], A[2*j+1]);
            *reinterpret_cast<uint2*>(rowp + 4*hi)      = make_uint2(dw[0], dw[1]);
            *reinterpret_cast<uint2*>(rowp + 8 + 4*hi)  = make_uint2(dw[2], dw[3]);
            *reinterpret_cast<uint2*>(rowp + 16 + 4*hi) = make_uint2(dw[4], dw[5]);
            *reinterpret_cast<uint2*>(rowp + 24 + 4*hi) = make_uint2(dw[6], dw[7]);
        }
    }
}

// ---------- kernel 1b: transpose Vcb[slot][32] -> Vt[d][slot] (bf16) ----------
__global__ __launch_bounds__(256) void vtrans_kernel(const unsigned short* __restrict__ Vcb,
                                                     unsigned short* __restrict__ Vt)
{
    const int bh = blockIdx.y;
    const int s0 = blockIdx.x * 256;
    __shared__ unsigned lds[256][17];
    const int t = threadIdx.x;
    const uint4* src = reinterpret_cast<const uint4*>(Vcb + ((size_t)bh * LSEQ + s0 + t) * DK);
    uint4 r0 = src[0], r1 = src[1], r2 = src[2], r3 = src[3];
    unsigned* lr = lds[t];
    lr[0]=r0.x;  lr[1]=r0.y;  lr[2]=r0.z;  lr[3]=r0.w;
    lr[4]=r1.x;  lr[5]=r1.y;  lr[6]=r1.z;  lr[7]=r1.w;
    lr[8]=r2.x;  lr[9]=r2.y;  lr[10]=r2.z; lr[11]=r2.w;
    lr[12]=r3.x; lr[13]=r3.y; lr[14]=r3.z; lr[15]=r3.w;
    __syncthreads();
    const int d = t & 31;
    const int c = (t >> 5) * 32;
    const int dw = d >> 1;
    const int dh = (d & 1) * 16;
    unsigned ow[16];
    #pragma unroll
    for (int i = 0; i < 16; ++i) {
        unsigned lo = (lds[c + 2*i][dw] >> dh) & 0xffffu;
        unsigned hv = (lds[c + 2*i + 1][dw] >> dh) & 0xffffu;
        ow[i] = lo | (hv << 16);
    }
    uint4* dstp = reinterpret_cast<uint4*>(Vt + ((size_t)bh * DK + d) * LSEQ + s0 + c);
    dstp[0] = make_uint4(ow[0],  ow[1],  ow[2],  ow[3]);
    dstp[1] = make_uint4(ow[4],  ow[5],  ow[6],  ow[7]);
    dstp[2] = make_uint4(ow[8],  ow[9],  ow[10], ow[11]);
    dstp[3] = make_uint4(ow[12], ow[13], ow[14], ow[15]);
}

// ---------- kernel 2: MFMA flash attention ----------
__global__ __launch_bounds__(128, 4) void attn_kernel(
    const unsigned short* __restrict__ Qb, const unsigned short* __restrict__ Kb,
    const unsigned short* __restrict__ Vt, const float* __restrict__ mask,
    const int* __restrict__ cnt, float* __restrict__ Hd)
{
    const int bh = blockIdx.y;
    const int b = bh >> 2;
    const int h = bh & 3;
    const int lane = threadIdx.x & 63;
    const int kw = threadIdx.x >> 6;              // key-half owner
    const int ql = lane & 31;
    const int hi = lane >> 5;
    const int q0 = blockIdx.x * 32;
    const int n = cnt[b];

    const uint4* Qp = reinterpret_cast<const uint4*>(Qb + ((size_t)bh * LSEQ + q0 + ql) * DK);
    const bf16x8 qf0 = as_bf16x8(Qp[hi]);         // Q[q=ql][d=8*hi+i]
    const bf16x8 qf1 = as_bf16x8(Qp[2 + hi]);     // d = 16+8*hi+i

    const unsigned short* Kbase = Kb + (size_t)bh * LSEQ * DK;
    const unsigned short* Vbase = Vt + ((size_t)bh * DK + ql) * LSEQ;

    f32x16 acc;
    #pragma unroll
    for (int r = 0; r < 16; ++r) acc[r] = 0.f;
    f32x16 zero;
    #pragma unroll
    for (int r = 0; r < 16; ++r) zero[r] = 0.f;
    float lacc = 0.f;

    auto tile = [&](int k0, bool pred) {
        const uint4* Kp = reinterpret_cast<const uint4*>(Kbase + (size_t)(k0 + ql) * DK);
        bf16x8 kf0 = as_bf16x8(Kp[hi]);           // K[key=ql][d=8*hi+i]
        bf16x8 kf1 = as_bf16x8(Kp[2 + hi]);
        f32x16 s = __builtin_amdgcn_mfma_f32_32x32x16_bf16(kf0, qf0, zero, 0, 0, 0);
        s = __builtin_amdgcn_mfma_f32_32x32x16_bf16(kf1, qf1, s, 0, 0, 0);
        const uint4* Vp = reinterpret_cast<const uint4*>(Vbase + k0);
        bf16x8 vf0 = as_bf16x8(Vp[hi]);           // Vt[d=ql][k0+8*hi+i]
        bf16x8 vf1 = as_bf16x8(Vp[2 + hi]);       // keys k0+16..k0+31
        unsigned w[8], sw[8];
        #pragma unroll
        for (int j = 0; j < 8; ++j) {
            float e0 = exp2f(s[2*j]   * SL);      // key = k0+(r&3)+8*(r>>2)+4*hi
            float e1 = exp2f(s[2*j+1] * SL);
            if (pred) {
                const int r0 = 2*j, r1 = 2*j + 1;
                if (k0 + (r0 & 3) + 8*(r0 >> 2) + 4*hi >= n) e0 = 0.f;
                if (k0 + (r1 & 3) + 8*(r1 >> 2) + 4*hi >= n) e1 = 0.f;
            }
            lacc += e0 + e1;
            w[j] = pack_bf2(e0, e1);
        }
        #pragma unroll
        for (int j = 0; j < 8; ++j) sw[j] = __shfl_xor(w[j], 32);
        uint4 b0 = hi ? make_uint4(sw[2], sw[3], w[2], w[3])
                      : make_uint4(w[0], w[1], sw[0], sw[1]);
        uint4 b1 = hi ? make_uint4(sw[6], sw[7], w[6], w[7])
                      : make_uint4(w[4], w[5], sw[4], sw[5]);
        acc = __builtin_amdgcn_mfma_f32_32x32x16_bf16(vf0, as_bf16x8(b0), acc, 0, 0, 0);
        acc = __builtin_amdgcn_mfma_f32_32x32x16_bf16(vf1, as_bf16x8(b1), acc, 0, 0, 0);
    };

    const int nfull = n & ~31;
    for (int k0 = kw * 32; k0 < nfull; k0 += 64) tile(k0, false);
    if (n & 31) {
        if (((nfull >> 5) & 1) == kw) tile(nfull, true);
    }

    __shared__ float red[64][18];
    if (kw == 1) {
        #pragma unroll
        for (int r = 0; r < 16; ++r) red[lane][r] = acc[r];
        red[lane][16] = lacc;
    }
    __syncthreads();
    if (kw == 0) {
        #pragma unroll
        for (int r = 0; r < 16; ++r) acc[r] += red[lane][r];
        lacc += red[lane][16];
        const float lf = lacc + __shfl_xor(lacc, 32);
        const float mq = mask[(size_t)b * LSEQ + q0 + ql];
        const float wgt = (lf > 0.f) ? (mq / lf) : 0.f;
        float* orow = Hd + ((size_t)b * LSEQ + q0 + ql) * DM + h * DK + 4 * hi;
        #pragma unroll
        for (int g = 0; g < 4; ++g) {            // d = 8g + 4hi + (0..3)
            float4 o = make_float4(acc[4*g]*wgt, acc[4*g+1]*wgt,
                                   acc[4*g+2]*wgt, acc[4*g+3]*wgt);
            *reinterpret_cast<float4*>(orow + 8*g) = o;
        }
    }
}

// ---------- kernel 3: output projection + transpose ----------
__global__ __launch_bounds__(256) void proj_kernel(const float* __restrict__ Hd,
    const float* __restrict__ Wo, float* __restrict__ out)
{
    const int b = blockIdx.x;
    const int l0 = blockIdx.y * 16;
    __shared__ float ht[16 * 129];
    const int tid = threadIdx.x;
    const float4* src = reinterpret_cast<const float4*>(Hd + ((size_t)b * LSEQ + l0) * DM);
    #pragma unroll
    for (int i = 0; i < 2; ++i) {
        int idx = tid + 256 * i;
        int r = idx >> 5;
        int c = (idx & 31) * 4;
        float4 v = src[idx];
        ht[r * 129 + c + 0] = v.x;
        ht[r * 129 + c + 1] = v.y;
        ht[r * 129 + c + 2] = v.z;
        ht[r * 129 + c + 3] = v.w;
    }
    __syncthreads();
    const int lt = tid & 15;
    const int jg = tid >> 4;
    float acc[8];
    #pragma unroll
    for (int i = 0; i < 8; ++i) acc[i] = 0.f;
    for (int i = 0; i < DM; ++i) {
        const float hv = ht[lt * 129 + i];
        const float4* w4 = reinterpret_cast<const float4*>(Wo + (size_t)i * DM + jg * 8);
        float4 w0 = w4[0], w1 = w4[1];
        acc[0] = fmaf(hv, w0.x, acc[0]);
        acc[1] = fmaf(hv, w0.y, acc[1]);
        acc[2] = fmaf(hv, w0.z, acc[2]);
        acc[3] = fmaf(hv, w0.w, acc[3]);
        acc[4] = fmaf(hv, w1.x, acc[4]);
        acc[5] = fmaf(hv, w1.y, acc[5]);
        acc[6] = fmaf(hv, w1.z, acc[6]);
        acc[7] = fmaf(hv, w1.w, acc[7]);
    }
    float* ob = out + (size_t)b * DM * LSEQ + (size_t)(jg * 8) * LSEQ + l0 + lt;
    #pragma unroll
    for (int j = 0; j < 8; ++j)
        ob[(size_t)j * LSEQ] = acc[j];
}

extern "C" void kernel_launch(void* const* d_in, const int* in_sizes, int n_in,
                              void* d_out, int out_size, void* d_ws, size_t ws_size,
                              hipStream_t stream)
{
    const float* x    = (const float*)d_in[0];
    const float* mask = (const float*)d_in[1];
    const float* Wq   = (const float*)d_in[2];
    const float* Wk   = (const float*)d_in[3];
    const float* Wv   = (const float*)d_in[4];
    const float* Wo   = (const float*)d_in[5];
    float* out = (float*)d_out;

    char* wsb = (char*)d_ws;
    const size_t NBF = (size_t)BATCH * NH * LSEQ * DK;      // 2,097,152 elems
    unsigned short* Qb  = (unsigned short*)wsb;             // 4MB
    unsigned short* Kb  = Qb + NBF;                         // 4MB
    unsigned short* Vcb = Kb + NBF;                         // 4MB
    unsigned short* Vt  = Vcb + NBF;                        // 4MB
    float* Hd = (float*)(wsb + 16ull * 1024 * 1024);        // 8MB (B,L,128) f32
    int* cpos = (int*)(wsb + 24ull * 1024 * 1024);
    int* cnt  = cpos + (size_t)BATCH * LSEQ;

    scan_kernel<<<dim3(BATCH), dim3(256), 0, stream>>>(mask, cpos, cnt);
    qkv_mfma_kernel<<<dim3(BATCH, 3, LSEQ / 64), dim3(256), 0, stream>>>(
        x, Wq, Wk, Wv, mask, cpos, Qb, Kb, Vcb);
    vtrans_kernel<<<dim3(LSEQ / 256, BATCH * NH), dim3(256), 0, stream>>>(Vcb, Vt);
    attn_kernel<<<dim3(LSEQ / 32, BATCH * NH), dim3(128), 0, stream>>>(
        Qb, Kb, Vt, mask, cnt, Hd);
    proj_kernel<<<dim3(BATCH, LSEQ / 16), dim3(256), 0, stream>>>(Hd, Wo, out);
}